// Round 10
// baseline (337.440 us; speedup 1.0000x reference)
//
#include <hip/hip_runtime.h>

#define IN_DIM 128
#define OUT_DIM 128
#define BIN_SHIFT 7          // 128 dst nodes per bin
#define BIN_NODES 128
#define NBIN_MAX 800         // ceil(100000/128) = 782
#define NPART 8              // frontier partitions (binA ordinal & 7)
#define CAPX 1024            // per-(partition,bin) capacity: mean ~515, +22 sd
#define CAP_LDS 4864         // per-bin staged total: mean 4092, sd 64 -> +12 sd
#define TILE_A 3072          // edges staged per binA block
#define NR 8                 // src ranges: 12500 nodes -> 3.2 MB Hb slice per L2
#define NKEY (BIN_NODES * NR)  // 1024 sort keys: local_dst*NR + range

typedef __attribute__((ext_vector_type(8))) short bf16x8;
typedef __attribute__((ext_vector_type(4))) float f32x4;
typedef __attribute__((ext_vector_type(2))) float f32x2;

__device__ inline unsigned short f2bf(float f) {
    unsigned u = __float_as_uint(f);
    unsigned r = (u + 0x7fff + ((u >> 16) & 1)) >> 16;  // RNE
    return (unsigned short)r;
}
__device__ inline float bflo(unsigned h) { return __uint_as_float(h << 16); }
__device__ inline float bfhi(unsigned h) { return __uint_as_float(h & 0xffff0000u); }

// ---------------------------------------------------------------------------
// pack_w + zero gcur (NPART*nbin cursors) in one launch (64 blocks x 256)
// ---------------------------------------------------------------------------
__global__ __launch_bounds__(256) void pack_w_zero(const float* __restrict__ W,
                                                   unsigned short* __restrict__ Wpack,
                                                   int* __restrict__ gcur, int nbin8) {
    int idx = blockIdx.x * 256 + threadIdx.x;
    if (idx < nbin8) gcur[idx] = 0;
    if (idx >= 16384) return;
    int j = idx & 7;
    int lane = (idx >> 3) & 63;
    int kc = (idx >> 9) & 3;
    int tn = idx >> 11;
    int k = kc * 32 + (lane >> 4) * 8 + j;
    int n = tn * 16 + (lane & 15);
    Wpack[idx] = f2bf(W[k * OUT_DIM + n]);
}

// ---------------------------------------------------------------------------
// Fused phase-1 (verbatim round-9): interleaved binA (sorted coalesced emit,
// partitioned frontiers) + gemm blocks.
// ---------------------------------------------------------------------------
struct BinSmem {
    int2 eL[TILE_A];
    int hist[NBIN_MAX];
    int s0[NBIN_MAX];
    int s1[NBIN_MAX];
    unsigned short bL[TILE_A];
    unsigned short idx[TILE_A];
    unsigned short bS[TILE_A];
};

__global__ __launch_bounds__(256) void phase1(
    const int* __restrict__ src, const int* __restrict__ dst,
    const float* __restrict__ vals, int* __restrict__ gcur,
    int2* __restrict__ entries, int n_edges, int nbin, int nA,
    const float* __restrict__ X, const unsigned short* __restrict__ Wpack,
    unsigned short* __restrict__ Hb, int n_rows, int nG) {
    __shared__ BinSmem sm;

    int b = blockIdx.x;
    int isGemm, widx;
    if (b < 2 * nG) {
        isGemm = (b & 1) == 0;
        widx = b >> 1;
    } else {
        isGemm = 0;
        widx = nG + (b - 2 * nG);
    }

    const int tid = threadIdx.x;

    if (!isGemm) {
        const int part = widx & (NPART - 1);
        const int base = widx * TILE_A;
        const int n0 = n_edges - base;
        if (n0 <= 0) return;
        const int n = (n0 < TILE_A) ? n0 : TILE_A;

        for (int i = tid; i < nbin; i += 256) sm.hist[i] = 0;
        __syncthreads();

        for (int i = tid; i < n; i += 256) {
            int d = dst[base + i];
            int s = src[base + i];
            float v = vals[base + i];
            int bin = d >> BIN_SHIFT;
            sm.eL[i] = make_int2(s | ((d & (BIN_NODES - 1)) << 17), __float_as_int(v));
            sm.bL[i] = (unsigned short)bin;
            atomicAdd(&sm.hist[bin], 1);
        }
        __syncthreads();

        for (int l = tid; l < nbin; l += 256) sm.s0[l] = sm.hist[l];
        __syncthreads();
        int* sin = sm.s0;
        int* sout = sm.s1;
        for (int dd = 1; dd < nbin; dd <<= 1) {
            for (int l = tid; l < nbin; l += 256)
                sout[l] = sin[l] + ((l >= dd) ? sin[l - dd] : 0);
            __syncthreads();
            int* t = sin; sin = sout; sout = t;
        }

        for (int l = tid; l < nbin; l += 256) {
            int c = sm.hist[l];
            int ex = sin[l] - c;
            int g = (c > 0) ? atomicAdd(&gcur[part * nbin + l], c) : 0;
            sout[l] = g - ex;
            sm.hist[l] = ex;
        }
        __syncthreads();

        for (int i = tid; i < n; i += 256) {
            int bb = sm.bL[i];
            int p = atomicAdd(&sm.hist[bb], 1);
            sm.idx[p] = (unsigned short)i;
            sm.bS[p] = (unsigned short)bb;
        }
        __syncthreads();

        for (int p = tid; p < n; p += 256) {
            int bb = sm.bS[p];
            int gp = sout[bb] + p;
            if (gp < CAPX)
                entries[((long long)(part * nbin + bb)) * CAPX + gp] = sm.eL[sm.idx[p]];
        }
        return;
    }

    // ----------------- gemm path -----------------
    int strip = widx * 4 + (tid >> 6);
    long long m0 = (long long)strip * 32;
    if (m0 >= n_rows) return;
    int lane = tid & 63;
    int quad = lane >> 4;
    int low = lane & 15;

    const bf16x8* B = (const bf16x8*)Wpack;

    long long r0 = m0 + low;
    long long r1 = m0 + 16 + low;
    if (r1 >= n_rows) r1 = n_rows - 1;
    if (r0 >= n_rows) r0 = n_rows - 1;

    f32x4 acc[2][8] = {};

#pragma unroll
    for (int kc = 0; kc < 4; ++kc) {
        const float4* p0 = (const float4*)(X + r0 * IN_DIM + kc * 32 + quad * 8);
        const float4* p1 = (const float4*)(X + r1 * IN_DIM + kc * 32 + quad * 8);
        float4 x0a = p0[0], x0b = p0[1];
        float4 x1a = p1[0], x1b = p1[1];
        bf16x8 afr0, afr1;
        afr0[0] = f2bf(x0a.x); afr0[1] = f2bf(x0a.y); afr0[2] = f2bf(x0a.z); afr0[3] = f2bf(x0a.w);
        afr0[4] = f2bf(x0b.x); afr0[5] = f2bf(x0b.y); afr0[6] = f2bf(x0b.z); afr0[7] = f2bf(x0b.w);
        afr1[0] = f2bf(x1a.x); afr1[1] = f2bf(x1a.y); afr1[2] = f2bf(x1a.z); afr1[3] = f2bf(x1a.w);
        afr1[4] = f2bf(x1b.x); afr1[5] = f2bf(x1b.y); afr1[6] = f2bf(x1b.z); afr1[7] = f2bf(x1b.w);
#pragma unroll
        for (int tn = 0; tn < 8; ++tn) {
            bf16x8 bfr = B[(tn * 4 + kc) * 64 + lane];
            acc[0][tn] = __builtin_amdgcn_mfma_f32_16x16x32_bf16(afr0, bfr, acc[0][tn], 0, 0, 0);
            acc[1][tn] = __builtin_amdgcn_mfma_f32_16x16x32_bf16(afr1, bfr, acc[1][tn], 0, 0, 0);
        }
    }

#pragma unroll
    for (int t = 0; t < 2; ++t) {
#pragma unroll
        for (int tn = 0; tn < 8; ++tn) {
#pragma unroll
            for (int r = 0; r < 4; ++r) {
                long long row = m0 + t * 16 + quad * 4 + r;
                if (row < n_rows) {
                    int col = tn * 16 + low;
                    Hb[row * OUT_DIM + col] = f2bf(acc[t][tn][r]);
                }
            }
        }
    }
}

// ---------------------------------------------------------------------------
// binB_gather (range-phased, REGISTER accumulation): 1024 threads = 16 waves,
// one block per 128-node bin; each wave owns 8 dst nodes.
//   A: stage 8 partition segments global->regs (1 slot/segment at 1024 thr);
//      1024-key histogram, key = local_dst*NR + src_range.
//   B: 1024-wide Hillis-Steele scan (1 key/thread).
//   C: scatter regs -> (node,range)-sorted LDS ent[].
//   D: RANGE-MAJOR outer loop; per range each wave processes its 8 nodes'
//      segments (k-loop fully unrolled -> acc[8] f32x2 statically indexed,
//      pure register accumulation, NO LDS atomics). Barrier per range keeps
//      all waves on the same 3.2MB Hb slice -> L2-resident (round-8-proven
//      FETCH mechanism, without the fp32-LDS-atomic poison).
//   E: per-wave register writeout with bias.
// LDS: 38912 ent + 3*4096 sort = 51200 B -> 2 blocks/CU, 32 waves/CU.
// ---------------------------------------------------------------------------
__global__ __launch_bounds__(1024) void binB_gather(
    const int2* __restrict__ entries, const int* __restrict__ gcur,
    const unsigned short* __restrict__ Hb, const float* __restrict__ bias,
    float* __restrict__ out, int n_nodes, int nbin) {
    __shared__ int2 ent[CAP_LDS];       // 38912 B
    __shared__ int hist[NKEY];          // 4096 B (counts, preserved)
    __shared__ int dbase[NKEY];         // 4096 B (exclusive offsets)
    __shared__ int cur[NKEY];           // 4096 B (scatter cursor)

    const int bin = blockIdx.x;
    const int tid = threadIdx.x;

    int scnt[NPART], sbase_[NPART];
    int tot = 0;
#pragma unroll
    for (int s = 0; s < NPART; ++s) {
        int c = gcur[s * nbin + bin];
        scnt[s] = (c < CAPX) ? c : CAPX;
        sbase_[s] = tot;
        tot += scnt[s];
    }

    hist[tid] = 0;
    __syncthreads();

    // --- A: global -> regs (1 slot per segment; 1024 threads = CAPX), hist ---
    const unsigned rdiv = (unsigned)((n_nodes + NR - 1) / NR);
    int2 e[NPART];
    int key[NPART];
    bool ok[NPART];
#pragma unroll
    for (int s = 0; s < NPART; ++s) {
        ok[s] = (tid < scnt[s]) && (sbase_[s] + tid < CAP_LDS);
        if (ok[s]) e[s] = entries[((long long)(s * nbin + bin)) * CAPX + tid];
    }
#pragma unroll
    for (int s = 0; s < NPART; ++s)
        if (ok[s]) {
            int ld = (e[s].x >> 17) & (BIN_NODES - 1);
            int rg = (int)((unsigned)(e[s].x & 0x1ffff) / rdiv);
            key[s] = ld * NR + rg;
            atomicAdd(&hist[key[s]], 1);
        }
    __syncthreads();

    // --- B: exclusive scan over 1024 keys (1 key/thread) ---
    dbase[tid] = hist[tid];
    __syncthreads();
    for (int d = 1; d < NKEY; d <<= 1) {
        int v = (tid >= d) ? dbase[tid - d] : 0;
        __syncthreads();
        dbase[tid] += v;
        __syncthreads();
    }
    {
        int ex = dbase[tid] - hist[tid];
        __syncthreads();
        dbase[tid] = ex;
        cur[tid] = ex;
    }
    __syncthreads();

    // --- C: scatter regs -> (node,range)-sorted LDS ---
#pragma unroll
    for (int s = 0; s < NPART; ++s)
        if (ok[s]) {
            int pos = atomicAdd(&cur[key[s]], 1);
            ent[pos] = e[s];
        }
    __syncthreads();

    // --- D: range-major gather, register accumulation ---
    const int wave = tid >> 6;
    const int lane = tid & 63;
    const unsigned short* hrow = Hb + lane * 2;
    float2 bb = ((const float2*)bias)[lane];

    f32x2 acc[8];
#pragma unroll
    for (int k = 0; k < 8; ++k) { acc[k][0] = bb.x; acc[k][1] = bb.y; }

    for (int r = 0; r < NR; ++r) {
#pragma unroll
        for (int k = 0; k < 8; ++k) {
            const int kk = (wave * 8 + k) * NR + r;
            const int beg = dbase[kk];
            const int end = beg + hist[kk];
            for (int i = beg; i < end; i += 8) {
                unsigned h[8];
                float v[8];
                bool okj[8];
#pragma unroll
                for (int j = 0; j < 8; ++j) {
                    okj[j] = (i + j < end);
                    if (okj[j]) {
                        int2 c = ent[i + j];
                        v[j] = __int_as_float(c.y);
                        h[j] = *(const unsigned*)(hrow + (long long)(c.x & 0x1ffff) * OUT_DIM);
                    }
                }
#pragma unroll
                for (int j = 0; j < 8; ++j)
                    if (okj[j]) {
                        f32x2 hv; hv[0] = bflo(h[j]); hv[1] = bfhi(h[j]);
                        f32x2 vv; vv[0] = v[j]; vv[1] = v[j];
                        acc[k] += vv * hv;
                    }
            }
        }
        __syncthreads();  // keep all 16 waves on range r's L2 slice together
    }

    // --- E: register writeout ---
    const int node0 = bin * BIN_NODES + wave * 8;
#pragma unroll
    for (int k = 0; k < 8; ++k) {
        int node = node0 + k;
        if (node < n_nodes) {
            float2 res; res.x = acc[k][0]; res.y = acc[k][1];
            ((float2*)(out + (long long)node * OUT_DIM))[lane] = res;
        }
    }
}

extern "C" void kernel_launch(void* const* d_in, const int* in_sizes, int n_in,
                              void* d_out, int out_size, void* d_ws, size_t ws_size,
                              hipStream_t stream) {
    const float* features  = (const float*)d_in[0];
    const int* edge_src    = (const int*)d_in[1];
    const int* edge_dst    = (const int*)d_in[2];
    const float* edge_vals = (const float*)d_in[3];
    const float* weight    = (const float*)d_in[4];
    const float* bias      = (const float*)d_in[5];

    const int n_nodes = in_sizes[0] / IN_DIM;
    const int n_edges = in_sizes[1];
    const int nbin = (n_nodes + BIN_NODES - 1) / BIN_NODES;  // 782

    // workspace layout (~77 MB)
    int2* entries       = (int2*)d_ws;                                 // NPART*nbin*CAPX
    unsigned short* Hb  = (unsigned short*)(entries + (long long)NPART * nbin * CAPX);
    unsigned short* Wp  = Hb + (long long)n_nodes * OUT_DIM;           // 16384
    int* gcur           = (int*)(Wp + 16384);                          // NPART*nbin

    float* out = (float*)d_out;

    pack_w_zero<<<64, 256, 0, stream>>>(weight, Wp, gcur, NPART * nbin);

    const int nA = (n_edges + TILE_A - 1) / TILE_A;
    const int n_strips = (n_nodes + 31) / 32;
    const int nG = (n_strips + 3) / 4;
    phase1<<<nA + nG, 256, 0, stream>>>(edge_src, edge_dst, edge_vals, gcur,
                                        entries, n_edges, nbin, nA,
                                        features, Wp, Hb, n_nodes, nG);

    binB_gather<<<nbin, 1024, 0, stream>>>(entries, gcur, Hb, bias, out, n_nodes, nbin);
}